// Round 3
// baseline (9656.741 us; speedup 1.0000x reference)
//
#include <hip/hip_runtime.h>
#include <math.h>
#include <stdint.h>

#define B 128
#define S 512
#define V 6000
#define E 100
#define H 256
#define G4 1024   /* 4*H */
#define T 9

/* W column split (float4 k-groups, 64 total = 256 cols per row)
   R3: NB=2 + 512 threads (2 waves/SIMD) + NO asm pin.
   [0,60)  WGLB : per-step global reloads (L2-hit, compiler-pipelined)
   [60,92) WLDS : 128 KB LDS slab
   [92,256) WSTR: streamed k-major, coalesced (layout = R2's k_prep) */
#define WGLB 15
#define WLDS 8
#define WSTR 41

/* workspace byte offsets (256-aligned) */
#define OFF_PEMB_F 0u
#define PEMB_BYTES (V*G4*4u)                    /* 24,576,000 */
#define OFF_PEMB_B (OFF_PEMB_F + PEMB_BYTES)
#define OFF_EMF    (OFF_PEMB_B + PEMB_BYTES)    /* 49,152,000 */
#define EM_BYTES   (B*S*T*4u)                   /* 2,359,296 */
#define OFF_EMB    (OFF_EMF + EM_BYTES)
#define OFF_BP     (OFF_EMB + EM_BYTES)         /* 53,870,592 */
#define BP_BYTES   ((S-1)*B*16u)                /* 1,046,528 */
#define OFF_LT     (OFF_BP + BP_BYTES)
#define OFF_PT     (OFF_LT + 512u)
/* Streamed-W (2 dirs x 41 groups x 1024 rows x 16 B = 1,343,488 B) OVERLAYS
   the BP/LT/PT region: k_prep writes it and k_lstm reads it strictly BEFORE
   k_vit/k_back write BP/LT/PT (stream-ordered). */
#define OFF_WSTREAM OFF_BP

__device__ __forceinline__ float sigf(float x) { return 1.0f / (1.0f + expf(-x)); }

/* pemb[v][g4] = bias[g4] + sum_e emb[v][e] * W_ih[g4][e],  g4 = q*H + j */
__global__ __launch_bounds__(256) void k_pemb(const float* __restrict__ emb,
                                              const float* __restrict__ wf, const float* __restrict__ bf,
                                              const float* __restrict__ wb, const float* __restrict__ bb,
                                              char* __restrict__ ws) {
    int blk = blockIdx.x;                   /* 0..749 */
    int d   = blk >= 375;
    int vb  = d ? blk - 375 : blk;
    const float* W    = d ? wb : wf;
    const float* bias = d ? bb : bf;
    float* pe = (float*)(ws + (d ? OFF_PEMB_B : OFF_PEMB_F));

    __shared__ float es[16 * E];
    for (int i = threadIdx.x; i < 16 * E; i += 256) es[i] = emb[vb * 16 * E + i];
    __syncthreads();

    int j = threadIdx.x;
    float acc[4][16];
    #pragma unroll
    for (int q = 0; q < 4; q++) {
        float bq = bias[q * H + j];
        #pragma unroll
        for (int v = 0; v < 16; v++) acc[q][v] = bq;
    }
    for (int e = 0; e < E; e++) {
        float w0 = W[(0 * H + j) * E + e];
        float w1 = W[(1 * H + j) * E + e];
        float w2 = W[(2 * H + j) * E + e];
        float w3 = W[(3 * H + j) * E + e];
        #pragma unroll
        for (int v = 0; v < 16; v++) {
            float x = es[v * E + e];
            acc[0][v] += w0 * x; acc[1][v] += w1 * x;
            acc[2][v] += w2 * x; acc[3][v] += w3 * x;
        }
    }
    for (int v = 0; v < 16; v++)
        #pragma unroll
        for (int q = 0; q < 4; q++)
            pe[(vb * 16 + v) * G4 + q * H + j] = acc[q][v];
}

/* streamed-W layout: wstr[(d*WSTR + g)*1024 + r] = {W_d[r][92+4g .. +3]}
   -> per step, lane r loads consecutive float4 (coalesced 1 KB/wave-inst) */
__global__ __launch_bounds__(256) void k_prep(const float* __restrict__ whhf,
                                              const float* __restrict__ whhb,
                                              char* __restrict__ ws) {
    int tid = blockIdx.x * 256 + threadIdx.x;   /* 2*41*1024 = 83968 */
    if (tid >= 2 * WSTR * 1024) return;
    int d   = tid >= WSTR * 1024;
    int idx = d ? tid - WSTR * 1024 : tid;
    int g = idx >> 10, r = idx & 1023;
    const float* whh = d ? whhb : whhf;
    float4* wstr = (float4*)(ws + OFF_WSTREAM);
    const float4* src = (const float4*)(whh + (size_t)r * H + 4 * (WGLB + WLDS));
    wstr[((size_t)(d * WSTR + g) << 10) + r] = src[g];
}

/* R3 k_lstm: 128 blocks (dir d = blk>>6, pair p -> batches 2p,2p+1) x 512 thr
   = 8 waves = 2 waves/SIMD (latency hiding, R0's regime). Thread t owns gate
   rows {t, t+512} for BOTH batches (4 accumulators). No asm pin (R1 spill
   lesson): WGLB cols are plain per-step global reloads the compiler
   software-pipelines. Two-barrier step, single hs buffer (R1's verified
   protocol). Per-step model: L2 14.8 MB/XCD -> 3.45us; VALU 2.0us (overlap);
   ds ~1.4us (overlap) -> step ~4.5-5.5us. */
__global__ __attribute__((amdgpu_flat_work_group_size(512, 512), amdgpu_waves_per_eu(2, 2)))
void k_lstm(const int* __restrict__ data,
            const float* __restrict__ whhf,
            const float* __restrict__ whhb,
            const float* __restrict__ mlpW,
            char* __restrict__ ws) {
    int blk = blockIdx.x;                      /* 0..127 */
    int d = blk >> 6, p = blk & 63;
    int b0 = 2 * p, b1 = b0 + 1;
    const float* whh = d ? whhb : whhf;
    const float* pe  = (const float*)(ws + (d ? OFF_PEMB_B : OFF_PEMB_F));
    float* emdst = (float*)(ws + (d ? OFF_EMB : OFF_EMF));
    const float4* wstr = (const float4*)(ws + OFF_WSTREAM) + ((size_t)(d * WSTR) << 10);

    __shared__ __align__(16) float hs[2][H];   /* [batch][unit], 2 KB */
    __shared__ float4 sW[WLDS << 10];          /* 128 KB */
    __shared__ float  gbuf[2][G4];             /* [batch][row], 8 KB */
    __shared__ float  red[2][T][4];            /* [batch][tag][wave&3] */
    __shared__ int    toks[2][S];              /* 4 KB */

    int t = threadIdx.x;                       /* 0..511 */
    int r0 = t, r1 = t + 512;

    const float4* wrow0 = (const float4*)(whh + (size_t)r0 * H);
    const float4* wrow1 = (const float4*)(whh + (size_t)r1 * H);

    /* stage LDS slab: groups WGLB..WGLB+WLDS-1 for both owned rows */
    #pragma unroll
    for (int g = 0; g < WLDS; g++) {
        sW[(g << 10) + r0] = wrow0[WGLB + g];
        sW[(g << 10) + r1] = wrow1[WGLB + g];
    }

    toks[0][t] = data[b0 * S + t];             /* S == 512 == blockDim */
    toks[1][t] = data[b1 * S + t];

    float mw[T];
    {
        int j = t & 255;
        #pragma unroll
        for (int tt = 0; tt < T; tt++) mw[tt] = mlpW[tt * (2 * H) + d * H + j];
    }
    if (t < 256) hs[0][t] = 0.0f; else hs[1][t - 256] = 0.0f;
    float cst = 0.0f;
    __syncthreads();

    const float4* h0p = (const float4*)&hs[0][0];
    const float4* h1p = (const float4*)&hs[1][0];
    const float4* wsp0 = wstr + r0;
    const float4* wsp1 = wstr + r1;

    float pf00, pf01, pf10, pf11;   /* pf<row><batch> */
    {
        int sp0 = d ? (S - 1) : 0;
        size_t tk0 = (size_t)toks[0][sp0];
        size_t tk1 = (size_t)toks[1][sp0];
        pf00 = pe[(tk0 << 10) + r0];
        pf10 = pe[(tk0 << 10) + r1];
        pf01 = pe[(tk1 << 10) + r0];
        pf11 = pe[(tk1 << 10) + r1];
    }

    for (int ss = 0; ss < S; ss++) {
        int sp = d ? (S - 1 - ss) : ss;
        float a00 = pf00, a01 = pf01;          /* row r0: batch0, batch1 */
        float a10 = pf10, a11 = pf11;          /* row r1: batch0, batch1 */
        if (ss + 1 < S) {
            int spn = d ? (S - 2 - ss) : (ss + 1);
            size_t tk0 = (size_t)toks[0][spn];
            size_t tk1 = (size_t)toks[1][spn];
            pf00 = pe[(tk0 << 10) + r0];
            pf10 = pe[(tk0 << 10) + r1];
            pf01 = pe[(tk1 << 10) + r0];
            pf11 = pe[(tk1 << 10) + r1];
        }

        /* global-W phase: groups 0..14 (cols 0..59), re-read each step (L2) */
        #pragma unroll
        for (int g = 0; g < WGLB; g++) {
            float4 w0 = wrow0[g];
            float4 w1 = wrow1[g];
            float4 h0 = h0p[g], h1 = h1p[g];
            a00 = fmaf(w0.x, h0.x, a00);  a01 = fmaf(w0.x, h1.x, a01);
            a10 = fmaf(w1.x, h0.x, a10);  a11 = fmaf(w1.x, h1.x, a11);
            a00 = fmaf(w0.y, h0.y, a00);  a01 = fmaf(w0.y, h1.y, a01);
            a10 = fmaf(w1.y, h0.y, a10);  a11 = fmaf(w1.y, h1.y, a11);
            a00 = fmaf(w0.z, h0.z, a00);  a01 = fmaf(w0.z, h1.z, a01);
            a10 = fmaf(w1.z, h0.z, a10);  a11 = fmaf(w1.z, h1.z, a11);
            a00 = fmaf(w0.w, h0.w, a00);  a01 = fmaf(w0.w, h1.w, a01);
            a10 = fmaf(w1.w, h0.w, a10);  a11 = fmaf(w1.w, h1.w, a11);
        }
        /* LDS-W phase: groups 15..22 (cols 60..91) */
        #pragma unroll
        for (int g = 0; g < WLDS; g++) {
            float4 w0 = sW[(g << 10) + r0];
            float4 w1 = sW[(g << 10) + r1];
            float4 h0 = h0p[WGLB + g], h1 = h1p[WGLB + g];
            a00 = fmaf(w0.x, h0.x, a00);  a01 = fmaf(w0.x, h1.x, a01);
            a10 = fmaf(w1.x, h0.x, a10);  a11 = fmaf(w1.x, h1.x, a11);
            a00 = fmaf(w0.y, h0.y, a00);  a01 = fmaf(w0.y, h1.y, a01);
            a10 = fmaf(w1.y, h0.y, a10);  a11 = fmaf(w1.y, h1.y, a11);
            a00 = fmaf(w0.z, h0.z, a00);  a01 = fmaf(w0.z, h1.z, a01);
            a10 = fmaf(w1.z, h0.z, a10);  a11 = fmaf(w1.z, h1.z, a11);
            a00 = fmaf(w0.w, h0.w, a00);  a01 = fmaf(w0.w, h1.w, a01);
            a10 = fmaf(w1.w, h0.w, a10);  a11 = fmaf(w1.w, h1.w, a11);
        }
        /* streamed phase: groups 23..63 (cols 92..255), coalesced from L2 */
        #pragma unroll 4
        for (int g = 0; g < WSTR; g++) {
            float4 w0 = wsp0[(size_t)g << 10];
            float4 w1 = wsp1[(size_t)g << 10];
            float4 h0 = h0p[WGLB + WLDS + g], h1 = h1p[WGLB + WLDS + g];
            a00 = fmaf(w0.x, h0.x, a00);  a01 = fmaf(w0.x, h1.x, a01);
            a10 = fmaf(w1.x, h0.x, a10);  a11 = fmaf(w1.x, h1.x, a11);
            a00 = fmaf(w0.y, h0.y, a00);  a01 = fmaf(w0.y, h1.y, a01);
            a10 = fmaf(w1.y, h0.y, a10);  a11 = fmaf(w1.y, h1.y, a11);
            a00 = fmaf(w0.z, h0.z, a00);  a01 = fmaf(w0.z, h1.z, a01);
            a10 = fmaf(w1.z, h0.z, a10);  a11 = fmaf(w1.z, h1.z, a11);
            a00 = fmaf(w0.w, h0.w, a00);  a01 = fmaf(w0.w, h1.w, a01);
            a10 = fmaf(w1.w, h0.w, a10);  a11 = fmaf(w1.w, h1.w, a11);
        }
        gbuf[0][r0] = a00;  gbuf[1][r0] = a01;
        gbuf[0][r1] = a10;  gbuf[1][r1] = a11;
        __syncthreads();   /* B1: gates complete, hs reads done */

        {
            int bi = t >> 8, j = t & 255;
            float gi = gbuf[bi][j],         gf = gbuf[bi][H + j];
            float gg = gbuf[bi][2 * H + j], go = gbuf[bi][3 * H + j];
            float ig = sigf(gi), fg = sigf(gf), tg = tanhf(gg), og = sigf(go);
            cst = fg * cst + ig * tg;
            float hn = og * tanhf(cst);
            hs[bi][j] = hn;
            int l = t & 63, wv = (t >> 6) & 3;
            #pragma unroll
            for (int tt = 0; tt < T; tt++) {
                float v = hn * mw[tt];
                v += __shfl_xor(v, 32, 64); v += __shfl_xor(v, 16, 64);
                v += __shfl_xor(v, 8, 64);  v += __shfl_xor(v, 4, 64);
                v += __shfl_xor(v, 2, 64);  v += __shfl_xor(v, 1, 64);
                if (l == 0) red[bi][tt][wv] = v;
            }
        }
        __syncthreads();   /* B2: hs updated + red ready */
        if (t < T)
            emdst[((size_t)b0 * S + sp) * T + t] =
                red[0][t][0] + red[0][t][1] + red[0][t][2] + red[0][t][3];
        else if (t >= 64 && t < 64 + T) {
            int tt = t - 64;
            emdst[((size_t)b1 * S + sp) * T + tt] =
                red[1][tt][0] + red[1][tt][1] + red[1][tt][2] + red[1][tt][3];
        }
    }
}

/* Viterbi forward: one wave per batch, lane t = tag. Strict-> ascending scan
   matches jnp.argmax first-index tie-breaking. */
__global__ __launch_bounds__(64) void k_vit(const int* __restrict__ data,
                                            const float* __restrict__ strans,
                                            const float* __restrict__ trans,
                                            const float* __restrict__ etrans,
                                            const float* __restrict__ mlpb,
                                            float* __restrict__ out,
                                            char* __restrict__ ws) {
    int b = blockIdx.x, t = threadIdx.x;
    const float* emf = (const float*)(ws + OFF_EMF);
    const float* emb = (const float*)(ws + OFF_EMB);
    char* bp = ws + OFF_BP;
    int*  lt = (int*)(ws + OFF_LT);
    bool act = t < T;

    float trp[T];
    float mb = 0.0f;
    if (act) {
        #pragma unroll
        for (int p = 0; p < T; p++) trp[p] = trans[p * T + t];
        mb = mlpb[t];
    }
    float score = -1e30f;
    if (act) score = strans[t] + emf[(b * S) * T + t] + emb[(b * S) * T + t] + mb;

    for (int s = 1; s < S; s++) {
        float e = 0.0f;
        if (act) e = emf[(b * S + s) * T + t] + emb[(b * S + s) * T + t] + mb;
        float best = __shfl(score, 0, 64) + trp[0];
        int bpi = 0;
        #pragma unroll
        for (int p = 1; p < T; p++) {
            float cand = __shfl(score, p, 64) + trp[p];
            if (cand > best) { best = cand; bpi = p; }
        }
        int m = data[b * S + s] != 0;
        if (act) {
            score = m ? (best + e) : score;
            bp[((size_t)(s - 1) * B + b) * 16 + t] = (char)bpi;
        }
    }
    float fin = act ? score + etrans[t] : -1e30f;
    float bv = __shfl(fin, 0, 64);
    int bi = 0;
    #pragma unroll
    for (int p = 1; p < T; p++) {
        float v = __shfl(fin, p, 64);
        if (v > bv) { bv = v; bi = p; }
    }
    if (t == 0) { out[B * S + b] = bv; lt[b] = bi; }
}

/* Backtrack: thread = batch; bp row address is tag-independent -> pipelined loads */
__global__ __launch_bounds__(128) void k_back(const int* __restrict__ data, char* __restrict__ ws) {
    int b = threadIdx.x;
    const int4* bp4 = (const int4*)(ws + OFF_BP);
    const int*  lt  = (const int*)(ws + OFF_LT);
    int* pt = (int*)(ws + OFF_PT);
    int tag = lt[b];
    pt[(S - 1) * B + b] = tag;
    for (int p = S - 2; p >= 0; p--) {
        int4 r = bp4[(size_t)p * B + b];
        int m = data[b * S + p + 1] != 0;
        unsigned w = (unsigned)(tag < 8 ? (tag < 4 ? r.x : r.y) : r.z);
        int nt = (int)((w >> ((tag & 3) * 8)) & 0xff);
        tag = m ? nt : tag;
        pt[p * B + b] = tag;
    }
}

/* paths -> float output with mask zeroing */
__global__ __launch_bounds__(256) void k_fin(const int* __restrict__ data,
                                             float* __restrict__ out,
                                             const char* __restrict__ ws) {
    int tid = blockIdx.x * 256 + threadIdx.x;   /* 65536 */
    const int* pt = (const int*)(ws + OFF_PT);
    int b = tid >> 9, p = tid & 511;
    out[tid] = (data[tid] != 0) ? (float)pt[p * B + b] : 0.0f;
}

extern "C" void kernel_launch(void* const* d_in, const int* in_sizes, int n_in,
                              void* d_out, int out_size, void* d_ws, size_t ws_size,
                              hipStream_t stream) {
    const int*   data = (const int*)d_in[0];
    /* d_in[1] = mask (bool) — unused; mask == (data != 0) */
    const float* emb  = (const float*)d_in[2];
    const float* wihf = (const float*)d_in[3];
    const float* whhf = (const float*)d_in[4];
    const float* bf   = (const float*)d_in[5];
    const float* wihb = (const float*)d_in[6];
    const float* whhb = (const float*)d_in[7];
    const float* bb   = (const float*)d_in[8];
    const float* mlpW = (const float*)d_in[9];
    const float* mlpb = (const float*)d_in[10];
    const float* st   = (const float*)d_in[11];
    const float* tr   = (const float*)d_in[12];
    const float* et   = (const float*)d_in[13];
    float* out = (float*)d_out;
    char*  ws  = (char*)d_ws;

    hipLaunchKernelGGL(k_pemb, dim3(750),  dim3(256), 0, stream, emb, wihf, bf, wihb, bb, ws);
    hipLaunchKernelGGL(k_prep, dim3(328),  dim3(256), 0, stream, whhf, whhb, ws);
    hipLaunchKernelGGL(k_lstm, dim3(128),  dim3(512), 0, stream, data, whhf, whhb, mlpW, ws);
    hipLaunchKernelGGL(k_vit,  dim3(128),  dim3(64),  0, stream, data, st, tr, et, mlpb, out, ws);
    hipLaunchKernelGGL(k_back, dim3(1),    dim3(128), 0, stream, data, ws);
    hipLaunchKernelGGL(k_fin,  dim3(256),  dim3(256), 0, stream, data, out, ws);
}

// Round 5
// 5254.448 us; speedup vs baseline: 1.8378x; 1.8378x over previous
//
#include <hip/hip_runtime.h>
#include <math.h>
#include <stdint.h>

#define B 128
#define S 512
#define V 6000
#define E 100
#define H 256
#define G4 1024   /* 4*H */
#define T 9

/* W column split (float4 k-groups, 64 total = 256 cols per row)
   R5 = R0 anchor with WLDS 3->8 (48->128 KB slab), WSTR 41->36.
   R4 LESSON: static LDS 154.8 KB aborts (usable ceiling < ~151 KB);
   this config totals 138,384 B, under R3's proven 145,696 B. */
#define WREG 20            /* cols [0,80)  "pinned": forces ~160 live load results
                              = deep load pipeline (prev-session R9/R13 win) */
#define WLDS 8             /* cols [80,112) in LDS slab (128 KB) */
#define WSTR 36            /* cols [112,256) streamed k-major (576 KB/step/dir) */

/* workspace byte offsets (256-aligned) */
#define OFF_PEMB_F 0u
#define PEMB_BYTES (V*G4*4u)                    /* 24,576,000 */
#define OFF_PEMB_B (OFF_PEMB_F + PEMB_BYTES)
#define OFF_EMF    (OFF_PEMB_B + PEMB_BYTES)    /* 49,152,000 */
#define EM_BYTES   (B*S*T*4u)                   /* 2,359,296 */
#define OFF_EMB    (OFF_EMF + EM_BYTES)
#define OFF_BP     (OFF_EMB + EM_BYTES)         /* 53,870,592 */
#define BP_BYTES   ((S-1)*B*16u)                /* 1,046,528 */
#define OFF_LT     (OFF_BP + BP_BYTES)
#define OFF_PT     (OFF_LT + 512u)
/* Streamed-W (2 dirs x 36 groups x 1024 rows x 16 B = 1,179,648 B) OVERLAYS
   the BP/LT/PT region: k_prep writes it and k_lstm reads it strictly BEFORE
   k_vit/k_back write BP/LT/PT (stream-ordered). R0 proved ws_size covers
   OFF_BP + 1,343,488; this needs only OFF_BP + 1,179,648. */
#define OFF_WSTREAM OFF_BP

__device__ __forceinline__ float sigf(float x) { return 1.0f / (1.0f + expf(-x)); }

/* pemb[v][g4] = bias[g4] + sum_e emb[v][e] * W_ih[g4][e],  g4 = q*H + j */
__global__ __launch_bounds__(256) void k_pemb(const float* __restrict__ emb,
                                              const float* __restrict__ wf, const float* __restrict__ bf,
                                              const float* __restrict__ wb, const float* __restrict__ bb,
                                              char* __restrict__ ws) {
    int blk = blockIdx.x;                   /* 0..749 */
    int d   = blk >= 375;
    int vb  = d ? blk - 375 : blk;
    const float* W    = d ? wb : wf;
    const float* bias = d ? bb : bf;
    float* pe = (float*)(ws + (d ? OFF_PEMB_B : OFF_PEMB_F));

    __shared__ float es[16 * E];
    for (int i = threadIdx.x; i < 16 * E; i += 256) es[i] = emb[vb * 16 * E + i];
    __syncthreads();

    int j = threadIdx.x;
    float acc[4][16];
    #pragma unroll
    for (int q = 0; q < 4; q++) {
        float bq = bias[q * H + j];
        #pragma unroll
        for (int v = 0; v < 16; v++) acc[q][v] = bq;
    }
    for (int e = 0; e < E; e++) {
        float w0 = W[(0 * H + j) * E + e];
        float w1 = W[(1 * H + j) * E + e];
        float w2 = W[(2 * H + j) * E + e];
        float w3 = W[(3 * H + j) * E + e];
        #pragma unroll
        for (int v = 0; v < 16; v++) {
            float x = es[v * E + e];
            acc[0][v] += w0 * x; acc[1][v] += w1 * x;
            acc[2][v] += w2 * x; acc[3][v] += w3 * x;
        }
    }
    for (int v = 0; v < 16; v++)
        #pragma unroll
        for (int q = 0; q < 4; q++)
            pe[(vb * 16 + v) * G4 + q * H + j] = acc[q][v];
}

/* streamed-W layout: wstr[(d*WSTR + g)*1024 + r] = {W_d[r][112+4g .. +3]}
   -> per step, lane r loads consecutive float4 (coalesced 1 KB/wave-inst) */
__global__ __launch_bounds__(256) void k_prep(const float* __restrict__ whhf,
                                              const float* __restrict__ whhb,
                                              char* __restrict__ ws) {
    int tid = blockIdx.x * 256 + threadIdx.x;   /* 2*36*1024 = 73728 */
    if (tid >= 2 * WSTR * 1024) return;
    int d   = tid >= WSTR * 1024;
    int idx = d ? tid - WSTR * 1024 : tid;
    int g = idx >> 10, r = idx & 1023;
    const float* whh = d ? whhb : whhf;
    float4* wstr = (float4*)(ws + OFF_WSTREAM);
    const float4* src = (const float4*)(whh + (size_t)r * H + 4 * (WREG + WLDS));
    wstr[((size_t)(d * WSTR + g) << 10) + r] = src[g];
}

/* Single-CU LSTM: 256 blocks (dir d = blk>>7, batch b = blk&127) x 512 thr.
   Thread t owns gate rows t and t+512. Per row: cols [0,80) asm-pinned loads
   (deep load pipeline), [80,112) in a 128 KB LDS slab, [112,256) streamed
   coalesced from L2 (576 KB/step, k-major). Identical to the verified R0
   anchor except WLDS 3->8. */
__global__ __attribute__((amdgpu_flat_work_group_size(512, 512), amdgpu_waves_per_eu(2, 2)))
void k_lstm(const int* __restrict__ data,
            const float* __restrict__ whhf,
            const float* __restrict__ whhb,
            const float* __restrict__ mlpW,
            char* __restrict__ ws) {
    int blk = blockIdx.x;
    int d = blk >> 7, b = blk & 127;
    const float* whh = d ? whhb : whhf;
    const float* pe  = (const float*)(ws + (d ? OFF_PEMB_B : OFF_PEMB_F));
    float* emdst = (float*)(ws + (d ? OFF_EMB : OFF_EMF));
    const float4* wstr = (const float4*)(ws + OFF_WSTREAM) + ((size_t)(d * WSTR) << 10);

    __shared__ __align__(16) float hs[H];      /* h_prev, 1 KB */
    __shared__ float4 sW[WLDS << 10];          /* 128 KB */
    __shared__ float  gbuf[G4];                /* 4 KB */
    __shared__ float  red[T][4];
    __shared__ int    toks[S];                 /* 2 KB */

    int t = threadIdx.x;                       /* 0..511 */
    int r0 = t, r1 = t + 512;

    const float4* wrow0 = (const float4*)(whh + (size_t)r0 * H);
    const float4* wrow1 = (const float4*)(whh + (size_t)r1 * H);
    float4 wA[WREG], wB[WREG];
    #pragma unroll
    for (int g = 0; g < WREG; g++) { wA[g] = wrow0[g]; wB[g] = wrow1[g]; }
    /* pin: consume the loads pre-loop; keeps a ~160-reg load pipeline live */
    #pragma unroll
    for (int g = 0; g < WREG; g++) {
        asm volatile("" : "+v"(wA[g].x), "+v"(wA[g].y), "+v"(wA[g].z), "+v"(wA[g].w));
        asm volatile("" : "+v"(wB[g].x), "+v"(wB[g].y), "+v"(wB[g].z), "+v"(wB[g].w));
    }
    #pragma unroll
    for (int g = 0; g < WLDS; g++) {
        sW[(g << 10) + r0] = wrow0[WREG + g];
        sW[(g << 10) + r1] = wrow1[WREG + g];
    }

    toks[t] = data[b * S + t];                 /* S == 512 == blockDim */

    float mw[T];
    if (t < 256) {
        #pragma unroll
        for (int tt = 0; tt < T; tt++) mw[tt] = mlpW[tt * (2 * H) + d * H + t];
    }
    if (t < H) hs[t] = 0.0f;
    float cst = 0.0f;
    __syncthreads();

    const float4* hs4 = (const float4*)hs;
    const float4* wsp0 = wstr + r0;
    const float4* wsp1 = wstr + r1;

    float pf0, pf1;
    {
        int sp0 = d ? (S - 1) : 0;
        size_t tok = (size_t)toks[sp0];
        pf0 = pe[(tok << 10) + r0];
        pf1 = pe[(tok << 10) + r1];
    }

    for (int ss = 0; ss < S; ss++) {
        int sp = d ? (S - 1 - ss) : ss;
        float acc0 = pf0, acc1 = pf1;
        if (ss + 1 < S) {
            int spn = d ? (S - 2 - ss) : (ss + 1);
            size_t tok = (size_t)toks[spn];
            pf0 = pe[(tok << 10) + r0];
            pf1 = pe[(tok << 10) + r1];
        }

        /* "register"-W phase: cols 0..79 */
        #pragma unroll
        for (int g = 0; g < WREG; g++) {
            float4 h4 = hs4[g];
            float4 a = wA[g], bb2 = wB[g];
            acc0 = fmaf(a.x, h4.x, acc0);  acc1 = fmaf(bb2.x, h4.x, acc1);
            acc0 = fmaf(a.y, h4.y, acc0);  acc1 = fmaf(bb2.y, h4.y, acc1);
            acc0 = fmaf(a.z, h4.z, acc0);  acc1 = fmaf(bb2.z, h4.z, acc1);
            acc0 = fmaf(a.w, h4.w, acc0);  acc1 = fmaf(bb2.w, h4.w, acc1);
        }
        /* LDS-W phase: cols 80..111 */
        #pragma unroll
        for (int g = 0; g < WLDS; g++) {
            float4 w0 = sW[(g << 10) + r0];
            float4 w1 = sW[(g << 10) + r1];
            float4 h4 = hs4[WREG + g];
            acc0 = fmaf(w0.x, h4.x, acc0);  acc1 = fmaf(w1.x, h4.x, acc1);
            acc0 = fmaf(w0.y, h4.y, acc0);  acc1 = fmaf(w1.y, h4.y, acc1);
            acc0 = fmaf(w0.z, h4.z, acc0);  acc1 = fmaf(w1.z, h4.z, acc1);
            acc0 = fmaf(w0.w, h4.w, acc0);  acc1 = fmaf(w1.w, h4.w, acc1);
        }
        /* streamed phase: cols 112..255 (bounded pipelining via unroll 4) */
        #pragma unroll 4
        for (int g = 0; g < WSTR; g++) {
            float4 w0 = wsp0[(size_t)g << 10];
            float4 w1 = wsp1[(size_t)g << 10];
            float4 h4 = hs4[WREG + WLDS + g];
            acc0 = fmaf(w0.x, h4.x, acc0);  acc1 = fmaf(w1.x, h4.x, acc1);
            acc0 = fmaf(w0.y, h4.y, acc0);  acc1 = fmaf(w1.y, h4.y, acc1);
            acc0 = fmaf(w0.z, h4.z, acc0);  acc1 = fmaf(w1.z, h4.z, acc1);
            acc0 = fmaf(w0.w, h4.w, acc0);  acc1 = fmaf(w1.w, h4.w, acc1);
        }
        gbuf[r0] = acc0;
        gbuf[r1] = acc1;
        __syncthreads();   /* B1: gates complete, hs reads done */

        if (t < 256) {
            float gi = gbuf[t], gf = gbuf[H + t], gg = gbuf[2 * H + t], go = gbuf[3 * H + t];
            float ig = sigf(gi), fg = sigf(gf), tg = tanhf(gg), og = sigf(go);
            cst = fg * cst + ig * tg;
            float hn = og * tanhf(cst);
            hs[t] = hn;
            int l = t & 63, wv = t >> 6;
            #pragma unroll
            for (int tt = 0; tt < T; tt++) {
                float v = hn * mw[tt];
                v += __shfl_xor(v, 32, 64); v += __shfl_xor(v, 16, 64);
                v += __shfl_xor(v, 8, 64);  v += __shfl_xor(v, 4, 64);
                v += __shfl_xor(v, 2, 64);  v += __shfl_xor(v, 1, 64);
                if (l == 0) red[tt][wv] = v;
            }
        }
        __syncthreads();   /* B2: hs updated + red ready */
        if (t < T)
            emdst[((size_t)b * S + sp) * T + t] = red[t][0] + red[t][1] + red[t][2] + red[t][3];
    }
}

/* Viterbi forward: one wave per batch, lane t = tag. Strict-> ascending scan
   matches jnp.argmax first-index tie-breaking. */
__global__ __launch_bounds__(64) void k_vit(const int* __restrict__ data,
                                            const float* __restrict__ strans,
                                            const float* __restrict__ trans,
                                            const float* __restrict__ etrans,
                                            const float* __restrict__ mlpb,
                                            float* __restrict__ out,
                                            char* __restrict__ ws) {
    int b = blockIdx.x, t = threadIdx.x;
    const float* emf = (const float*)(ws + OFF_EMF);
    const float* emb = (const float*)(ws + OFF_EMB);
    char* bp = ws + OFF_BP;
    int*  lt = (int*)(ws + OFF_LT);
    bool act = t < T;

    float trp[T];
    float mb = 0.0f;
    if (act) {
        #pragma unroll
        for (int p = 0; p < T; p++) trp[p] = trans[p * T + t];
        mb = mlpb[t];
    }
    float score = -1e30f;
    if (act) score = strans[t] + emf[(b * S) * T + t] + emb[(b * S) * T + t] + mb;

    for (int s = 1; s < S; s++) {
        float e = 0.0f;
        if (act) e = emf[(b * S + s) * T + t] + emb[(b * S + s) * T + t] + mb;
        float best = __shfl(score, 0, 64) + trp[0];
        int bpi = 0;
        #pragma unroll
        for (int p = 1; p < T; p++) {
            float cand = __shfl(score, p, 64) + trp[p];
            if (cand > best) { best = cand; bpi = p; }
        }
        int m = data[b * S + s] != 0;
        if (act) {
            score = m ? (best + e) : score;
            bp[((size_t)(s - 1) * B + b) * 16 + t] = (char)bpi;
        }
    }
    float fin = act ? score + etrans[t] : -1e30f;
    float bv = __shfl(fin, 0, 64);
    int bi = 0;
    #pragma unroll
    for (int p = 1; p < T; p++) {
        float v = __shfl(fin, p, 64);
        if (v > bv) { bv = v; bi = p; }
    }
    if (t == 0) { out[B * S + b] = bv; lt[b] = bi; }
}

/* Backtrack: thread = batch; bp row address is tag-independent -> pipelined loads */
__global__ __launch_bounds__(128) void k_back(const int* __restrict__ data, char* __restrict__ ws) {
    int b = threadIdx.x;
    const int4* bp4 = (const int4*)(ws + OFF_BP);
    const int*  lt  = (const int*)(ws + OFF_LT);
    int* pt = (int*)(ws + OFF_PT);
    int tag = lt[b];
    pt[(S - 1) * B + b] = tag;
    for (int p = S - 2; p >= 0; p--) {
        int4 r = bp4[(size_t)p * B + b];
        int m = data[b * S + p + 1] != 0;
        unsigned w = (unsigned)(tag < 8 ? (tag < 4 ? r.x : r.y) : r.z);
        int nt = (int)((w >> ((tag & 3) * 8)) & 0xff);
        tag = m ? nt : tag;
        pt[p * B + b] = tag;
    }
}

/* paths -> float output with mask zeroing */
__global__ __launch_bounds__(256) void k_fin(const int* __restrict__ data,
                                             float* __restrict__ out,
                                             const char* __restrict__ ws) {
    int tid = blockIdx.x * 256 + threadIdx.x;   /* 65536 */
    const int* pt = (const int*)(ws + OFF_PT);
    int b = tid >> 9, p = tid & 511;
    out[tid] = (data[tid] != 0) ? (float)pt[p * B + b] : 0.0f;
}

extern "C" void kernel_launch(void* const* d_in, const int* in_sizes, int n_in,
                              void* d_out, int out_size, void* d_ws, size_t ws_size,
                              hipStream_t stream) {
    const int*   data = (const int*)d_in[0];
    /* d_in[1] = mask (bool) — unused; mask == (data != 0) */
    const float* emb  = (const float*)d_in[2];
    const float* wihf = (const float*)d_in[3];
    const float* whhf = (const float*)d_in[4];
    const float* bf   = (const float*)d_in[5];
    const float* wihb = (const float*)d_in[6];
    const float* whhb = (const float*)d_in[7];
    const float* bb   = (const float*)d_in[8];
    const float* mlpW = (const float*)d_in[9];
    const float* mlpb = (const float*)d_in[10];
    const float* st   = (const float*)d_in[11];
    const float* tr   = (const float*)d_in[12];
    const float* et   = (const float*)d_in[13];
    float* out = (float*)d_out;
    char*  ws  = (char*)d_ws;

    hipLaunchKernelGGL(k_pemb, dim3(750),  dim3(256), 0, stream, emb, wihf, bf, wihb, bb, ws);
    hipLaunchKernelGGL(k_prep, dim3(288),  dim3(256), 0, stream, whhf, whhb, ws);
    hipLaunchKernelGGL(k_lstm, dim3(256),  dim3(512), 0, stream, data, whhf, whhb, mlpW, ws);
    hipLaunchKernelGGL(k_vit,  dim3(128),  dim3(64),  0, stream, data, st, tr, et, mlpb, out, ws);
    hipLaunchKernelGGL(k_back, dim3(1),    dim3(128), 0, stream, data, ws);
    hipLaunchKernelGGL(k_fin,  dim3(256),  dim3(256), 0, stream, data, out, ws);
}